// Round 7
// baseline (242.541 us; speedup 1.0000x reference)
//
#include <hip/hip_runtime.h>
#include <hip/hip_bf16.h>

// Inputs fp32, output fp32 (proven). Intermediates bf16 in ws.
#define HH    768
#define NHEAD 12
#define HDIM  64
#define BB    4
#define SS    2048
#define MM    (BB*SS)     // 8192 rows
#define NDIMS 5
#define WEL   (HH*HH)     // 589824 elements per weight matrix
#define LOG2E 1.44269504088896f
#define QSCALE 0.180336881f   // 0.125 * log2e

typedef unsigned short u16;
typedef __attribute__((ext_vector_type(8))) short short8;     // 8 bf16 (4 VGPRs)
typedef __attribute__((ext_vector_type(4))) float floatx4;    // 16x16 MFMA C/D
typedef __attribute__((ext_vector_type(16))) float floatx16;  // 32x32 MFMA C/D
typedef __attribute__((ext_vector_type(4))) unsigned int uint4v;
typedef __attribute__((ext_vector_type(2))) unsigned int uint2v;

__device__ __forceinline__ float bf2f(u16 u) {
    return __uint_as_float(((unsigned int)u) << 16);
}
__device__ __forceinline__ u16 f2bf(float f) {
    unsigned int x = __float_as_uint(f);
    unsigned int r = (x + 0x7fffu + ((x >> 16) & 1u)) >> 16;
    return (u16)r;
}
__device__ __forceinline__ unsigned int pack_bf16x2(float a, float b) {
    float2 f2 = make_float2(a, b);
    __hip_bfloat162 h2 = __float22bfloat162_rn(f2);
    return *reinterpret_cast<unsigned int*>(&h2);
}
// async global->LDS, 16 B per lane; LDS dest = wave-uniform base + lane*16
__device__ __forceinline__ void gld16(const u16* g, u16* l) {
    __builtin_amdgcn_global_load_lds(
        (const __attribute__((address_space(1))) unsigned int*)g,
        (__attribute__((address_space(3))) unsigned int*)l, 16, 0, 0);
}

// fp32 -> bf16, 8 elements/thread (fallback path)
__global__ __launch_bounds__(256) void f32_to_bf16(
    const float* __restrict__ in, u16* __restrict__ out, int n8)
{
    int i = blockIdx.x * 256 + threadIdx.x;
    if (i >= n8) return;
    float4 a = ((const float4*)in)[i*2];
    float4 b = ((const float4*)in)[i*2 + 1];
    ushort4 lo, hi;
    lo.x = f2bf(a.x); lo.y = f2bf(a.y); lo.z = f2bf(a.z); lo.w = f2bf(a.w);
    hi.x = f2bf(b.x); hi.y = f2bf(b.y); hi.z = f2bf(b.z); hi.w = f2bf(b.w);
    ((ushort4*)out)[i*2]     = lo;
    ((ushort4*)out)[i*2 + 1] = hi;
}

// Fused conversion: x (MM*HH) and 4 weight matrices -> bf16, one launch.
#define XCVT_BLKS ((MM*HH)/8/256)   // 3072
#define WCVT_BLKS (WEL/8/256)       // 288
__global__ __launch_bounds__(256) void cvt_all(
    const float* __restrict__ x,
    const float* __restrict__ W0, const float* __restrict__ W1,
    const float* __restrict__ W2, const float* __restrict__ W3,
    u16* __restrict__ xb, u16* __restrict__ wb)
{
    const int bid = blockIdx.x;
    const float* src;
    u16* dst;
    int i;
    if (bid < XCVT_BLKS) {
        src = x; dst = xb; i = bid * 256 + threadIdx.x;
    } else {
        const int wsel = (bid - XCVT_BLKS) / WCVT_BLKS;
        src = (wsel == 0) ? W0 : (wsel == 1) ? W1 : (wsel == 2) ? W2 : W3;
        dst = wb + (size_t)wsel * WEL;
        i = ((bid - XCVT_BLKS) % WCVT_BLKS) * 256 + threadIdx.x;
    }
    float4 a = ((const float4*)src)[i*2];
    float4 b = ((const float4*)src)[i*2 + 1];
    ushort4 lo, hi;
    lo.x = f2bf(a.x); lo.y = f2bf(a.y); lo.z = f2bf(a.z); lo.w = f2bf(a.w);
    hi.x = f2bf(b.x); hi.y = f2bf(b.y); hi.z = f2bf(b.z); hi.w = f2bf(b.w);
    ((ushort4*)dst)[i*2]     = lo;
    ((ushort4*)dst)[i*2 + 1] = hi;
}

// V [b*SS+key][h*64+d] bf16 -> vt [(b*12+h)*64+d][key] (per-head transposed).
// 64x64 tile per block via LDS pair-packing (same packing as old attn writeV).
__global__ __launch_bounds__(256) void v_transpose(
    const u16* __restrict__ V, u16* __restrict__ vt)
{
    __shared__ unsigned Ls[64][36];   // [d][keypair], row = 144 B (16B-aligned)
    const int t = threadIdx.x;
    const int kt = blockIdx.x, h = blockIdx.y, b = blockIdx.z;
    const int p  = t & 31;            // key pair: keys 2p, 2p+1
    const int dg = (t >> 5) * 8;      // 8 d values
    const u16* va = V + ((size_t)(b*SS + kt*64 + 2*p))*HH + h*HDIM + dg;
    const u16* vb = va + HH;
    uint4 A = *(const uint4*)va;
    uint4 Bv = *(const uint4*)vb;
    const unsigned* Aw = (const unsigned*)&A;
    const unsigned* Bw = (const unsigned*)&Bv;
    #pragma unroll
    for (int i = 0; i < 4; ++i) {
        unsigned a = Aw[i], c = Bw[i];
        Ls[dg + 2*i][p]     = (a & 0xffffu) | (c << 16);
        Ls[dg + 2*i + 1][p] = (a >> 16) | (c & 0xffff0000u);
    }
    __syncthreads();
    const int d = t >> 2, kc = (t & 3) * 8;   // 8 pairs = 16 keys
    uint4 o0 = *(const uint4*)&Ls[d][kc];
    uint4 o1 = *(const uint4*)&Ls[d][kc + 4];
    u16* dst = vt + ((size_t)((b*NHEAD + h)*HDIM + d))*SS + kt*64 + kc*2;
    *(uint4*)dst       = o0;
    *(uint4*)(dst + 8) = o1;
}

// ---- Fused QKV GEMM: 128x192 block, BK=64, global_load_lds staging,
// chunk-XOR-swizzled LDS (chunk c of row r stored at c^(r&7)).
// 4 waves (2Mx2N), each 64x96 via 32x32x16 MFMA: acc[2][3].
// Grid 12x64 = 768 blocks = 3.0/CU exact; LDS 40 KB; launch_bounds(256,3).
__global__ __launch_bounds__(256, 3) void gemm_gld_qkv(
    const u16* __restrict__ Xb, const u16* __restrict__ Wb3,
    const float* __restrict__ bq, const float* __restrict__ bk, const float* __restrict__ bv,
    u16* __restrict__ oq, u16* __restrict__ ok, u16* __restrict__ ov)
{
    __shared__ u16 Xs[128][64];   // 16 KB
    __shared__ u16 Ws[192][64];   // 24 KB
    const int t = threadIdx.x;
    const int w = t >> 6, lane = t & 63;
    const int wy = w >> 1, wx = w & 1;
    const int m = lane & 31, hh = lane >> 5;
    const int grow = lane >> 3;
    const int cg   = (lane & 7) ^ grow;

    // XCD-bijective swizzle: 768 = 8 XCDs x 96 = 8 i-panels x 12 j-tiles each.
    const int flat = blockIdx.x + 12 * blockIdx.y;
    const int swz  = (flat & 7) * 96 + (flat >> 3);
    const int j0 = (swz % 12) * 192;
    const int i0 = (swz / 12) * 128;
    const int sel = j0 / HH;                 // 0=q 1=k 2=v (192 | 768)
    const int lj  = j0 - sel * HH;
    const float* biasL = ((sel == 0) ? bq : (sel == 1) ? bk : bv) + lj;
    u16* outL = ((sel == 0) ? oq : (sel == 1) ? ok : ov) + lj;
    const u16* Wrows = Wb3 + (size_t)j0 * HH;

    floatx16 acc[2][3];
    #pragma unroll
    for (int am = 0; am < 2; ++am)
        #pragma unroll
        for (int bn = 0; bn < 3; ++bn)
            #pragma unroll
            for (int r = 0; r < 16; ++r) acc[am][bn][r] = 0.f;

    for (int k0 = 0; k0 < HH; k0 += 64) {
        __syncthreads();   // previous iter's frag reads complete
        #pragma unroll
        for (int j = 0; j < 4; ++j) {
            const int r = w*32 + j*8;
            gld16(Xb + (size_t)(i0 + r + grow)*HH + k0 + cg*8, &Xs[r][0]);
        }
        #pragma unroll
        for (int j = 0; j < 6; ++j) {
            const int r = w*48 + j*8;
            gld16(Wrows + (size_t)(r + grow)*HH + k0 + cg*8, &Ws[r][0]);
        }
        __syncthreads();   // drains vmcnt before barrier (compiler-inserted)

        #pragma unroll
        for (int kh = 0; kh < 4; ++kh) {
            const int ch = kh*2 + hh;
            short8 af[2], bf[3];
            #pragma unroll
            for (int am = 0; am < 2; ++am) {
                const int row = wy*64 + am*32 + m;
                af[am] = *(const short8*)&Xs[row][(ch ^ (m & 7))*8];
            }
            #pragma unroll
            for (int bn = 0; bn < 3; ++bn) {
                const int row = wx*96 + bn*32 + m;
                bf[bn] = *(const short8*)&Ws[row][(ch ^ (m & 7))*8];
            }
            #pragma unroll
            for (int am = 0; am < 2; ++am)
                #pragma unroll
                for (int bn = 0; bn < 3; ++bn)
                    acc[am][bn] = __builtin_amdgcn_mfma_f32_32x32x16_bf16(
                        af[am], bf[bn], acc[am][bn], 0, 0, 0);
        }
    }

    float bb[3];
    #pragma unroll
    for (int bn = 0; bn < 3; ++bn) bb[bn] = biasL[wx*96 + bn*32 + m];
    #pragma unroll
    for (int am = 0; am < 2; ++am)
        #pragma unroll
        for (int bn = 0; bn < 3; ++bn)
            #pragma unroll
            for (int r = 0; r < 16; ++r) {
                int row = i0 + wy*64 + am*32 + (r & 3) + 8*(r >> 2) + 4*hh;
                outL[(size_t)row*HH + wx*96 + bn*32 + m] = f2bf(acc[am][bn][r] + bb[bn]);
            }
}

// Output-projection GEMM: M-tile=64, N-tile=128 -> grid (6,128)=768 blocks
// (3 blocks/CU). Same staging/swizzle pattern.
__global__ __launch_bounds__(256) void gemm_gld_m64(
    const u16* __restrict__ Xb, const u16* __restrict__ Wb,
    const float* __restrict__ bias, u16* __restrict__ out)
{
    __shared__ u16 Xs[64][64];    // 8 KB
    __shared__ u16 Ws[128][64];   // 16 KB
    const int t = threadIdx.x;
    const int w = t >> 6, lane = t & 63;
    const int m = lane & 31, hh = lane >> 5;
    const int grow = lane >> 3;
    const int cg   = (lane & 7) ^ grow;

    // XCD-bijective swizzle: 768 = 8 x 96; each XCD gets 16 full M-panels.
    const int flat = blockIdx.x + 6 * blockIdx.y;
    const int swz  = (flat & 7) * 96 + (flat >> 3);
    const int j0 = (swz % 6) * 128;
    const int i0 = (swz / 6) * 64;

    floatx16 acc[2];
    #pragma unroll
    for (int am = 0; am < 2; ++am)
        #pragma unroll
        for (int r = 0; r < 16; ++r) acc[am][r] = 0.f;

    for (int k0 = 0; k0 < HH; k0 += 64) {
        __syncthreads();
        #pragma unroll
        for (int j = 0; j < 2; ++j) {
            const int r = w*16 + j*8;
            gld16(Xb + (size_t)(i0 + r + grow)*HH + k0 + cg*8, &Xs[r][0]);
        }
        #pragma unroll
        for (int j = 0; j < 4; ++j) {
            const int r = w*32 + j*8;
            gld16(Wb + (size_t)(j0 + r + grow)*HH + k0 + cg*8, &Ws[r][0]);
        }
        __syncthreads();

        #pragma unroll
        for (int kh = 0; kh < 4; ++kh) {
            const int ch = kh*2 + hh;
            short8 af[2], bf;
            af[0] = *(const short8*)&Xs[m][(ch ^ (m & 7))*8];
            af[1] = *(const short8*)&Xs[32 + m][(ch ^ (m & 7))*8];
            bf    = *(const short8*)&Ws[w*32 + m][(ch ^ (m & 7))*8];
            acc[0] = __builtin_amdgcn_mfma_f32_32x32x16_bf16(af[0], bf, acc[0], 0, 0, 0);
            acc[1] = __builtin_amdgcn_mfma_f32_32x32x16_bf16(af[1], bf, acc[1], 0, 0, 0);
        }
    }

    const float bb = bias[j0 + w*32 + m];
    #pragma unroll
    for (int am = 0; am < 2; ++am)
        #pragma unroll
        for (int r = 0; r < 16; ++r) {
            int row = i0 + am*32 + (r & 3) + 8*(r >> 2) + 4*hh;
            out[(size_t)row*HH + j0 + w*32 + m] = f2bf(acc[am][r] + bb);
        }
}

// Fallback (small ws): W fp32, cvt during staging — round-6 proven 16x16x32 kernel.
__global__ __launch_bounds__(256) void gemm_mfma_nt(
    const u16* __restrict__ Xb, const float* __restrict__ W,
    const float* __restrict__ bias, u16* __restrict__ out)
{
    __shared__ u16 Xs[128][40];
    __shared__ u16 Wt[64][40];
    const int t = threadIdx.x;
    const int w = t >> 6, lane = t & 63;
    const int c = lane & 15, qd = lane >> 4;
    const int i0 = blockIdx.y * 128, j0 = blockIdx.x * 64;
    const int xrow = t >> 1, xoff = (t & 1) * 16;
    const int wn = t >> 2, woff = (t & 3) * 8;

    floatx4 acc[2][4];
    #pragma unroll
    for (int mt = 0; mt < 2; ++mt)
        #pragma unroll
        for (int nt = 0; nt < 4; ++nt) acc[mt][nt] = (floatx4){0.f,0.f,0.f,0.f};

    for (int k0 = 0; k0 < HH; k0 += 32) {
        uint4 xa  = *(const uint4*)(Xb + (size_t)(i0 + xrow)*HH + k0 + xoff);
        uint4 xb2 = *(const uint4*)(Xb + (size_t)(i0 + xrow)*HH + k0 + xoff + 8);
        float4 wa = *(const float4*)(W + (size_t)(j0 + wn)*HH + k0 + woff);
        float4 wb = *(const float4*)(W + (size_t)(j0 + wn)*HH + k0 + woff + 4);
        __syncthreads();
        *(uint4*)&Xs[xrow][xoff]     = xa;
        *(uint4*)&Xs[xrow][xoff + 8] = xb2;
        ushort4 w0, w1;
        w0.x = f2bf(wa.x); w0.y = f2bf(wa.y); w0.z = f2bf(wa.z); w0.w = f2bf(wa.w);
        w1.x = f2bf(wb.x); w1.y = f2bf(wb.y); w1.z = f2bf(wb.z); w1.w = f2bf(wb.w);
        *(ushort4*)&Wt[wn][woff]     = w0;
        *(ushort4*)&Wt[wn][woff + 4] = w1;
        __syncthreads();

        short8 a0 = *(const short8*)&Xs[w*32 + c][qd*8];
        short8 a1 = *(const short8*)&Xs[w*32 + 16 + c][qd*8];
        #pragma unroll
        for (int nt = 0; nt < 4; ++nt) {
            short8 bfr = *(const short8*)&Wt[nt*16 + c][qd*8];
            acc[0][nt] = __builtin_amdgcn_mfma_f32_16x16x32_bf16(a0, bfr, acc[0][nt], 0, 0, 0);
            acc[1][nt] = __builtin_amdgcn_mfma_f32_16x16x32_bf16(a1, bfr, acc[1][nt], 0, 0, 0);
        }
    }

    float bv[4];
    #pragma unroll
    for (int nt = 0; nt < 4; ++nt) bv[nt] = bias[j0 + nt*16 + c];
    #pragma unroll
    for (int mt = 0; mt < 2; ++mt)
        #pragma unroll
        for (int nt = 0; nt < 4; ++nt)
            #pragma unroll
            for (int r = 0; r < 4; ++r)
                out[(size_t)(i0 + w*32 + mt*16 + qd*4 + r)*HH + j0 + nt*16 + c] =
                    f2bf(acc[mt][nt][r] + bv[nt]);
}

// ---- 32x32 MFMA flash attention (QBLK=128, 768 blocks, 3 blocks/CU),
// in-register softmax (T12), XCD-bijective swizzle (T1), T5 setprio.
// V pre-transposed to [(b*12+h)*64+d][key] -> staged via gld16 exactly like K
// (no reg-pack, no ds_writes). Vs chunk c of d-row holds global chunk c^(d&7).
__global__ __launch_bounds__(256, 3) void attn_mfma32(
    const u16* __restrict__ Q, const u16* __restrict__ K, const u16* __restrict__ vt,
    const float* __restrict__ dim_biases, const int* __restrict__ mask,
    const int* __restrict__ dim_idx_p, u16* __restrict__ ctx)
{
    __shared__ u16 Ks[2][64][64];    // [buf][key][d], chunk c holds global chunk c^(key&7)
    __shared__ u16 Vs[2][64][64];    // [buf][d][key], chunk c holds global chunk c^(d&7)
    __shared__ float madd[2][64];    // per-key: mask ? db2 : -1e30

    const int t = threadIdx.x;
    const int w = t >> 6, lane = t & 63;
    const int ql = lane & 31, hi = lane >> 5;
    const int sw7 = ql & 7;

    // XCD-bijective swizzle: 768 blocks = 8 XCDs x 96.
    const int flat = blockIdx.x + 16 * (blockIdx.y + 12 * blockIdx.z);
    const int swz  = (flat & 7) * 96 + (flat >> 3);
    const int q0 = (swz & 15) * 128;
    const int h  = (swz >> 4) % NHEAD;
    const int b  = swz / (16 * NHEAD);

    const int didx = *dim_idx_p;
    const float db2 = ((didx < NDIMS) ? dim_biases[didx*NHEAD + h] : 0.f) * LOG2E;

    // staging geometry (gld16): 8 rows x 8 chunks per instr, chunk-XOR swizzle
    const int grow = lane >> 3;
    const int cg   = (lane & 7) ^ grow;

    const u16* Vrows = vt + (size_t)(b*NHEAD + h)*HDIM*SS;   // 64 rows of SS keys

    short8 ones;
    #pragma unroll
    for (int j = 0; j < 8; ++j) ones[j] = (short)0x3F80;   // bf16 1.0

    // Q in registers: B-frag qv[s][j] = QSCALE * Q[q0+w*32+ql][s*16 + 8*hi + j]
    short8 qv[4];
    {
        const u16* qsrc = Q + ((size_t)(b*SS + q0 + w*32 + ql))*HH + h*HDIM + 8*hi;
        #pragma unroll
        for (int s = 0; s < 4; ++s) {
            ushort4 u0 = *(const ushort4*)(qsrc + s*16);
            ushort4 u1 = *(const ushort4*)(qsrc + s*16 + 4);
            const u16 uu[8] = {u0.x,u0.y,u0.z,u0.w,u1.x,u1.y,u1.z,u1.w};
            #pragma unroll
            for (int j = 0; j < 8; ++j)
                qv[s][j] = (short)f2bf(bf2f(uu[j]) * QSCALE);
        }
    }

    floatx16 o[2], lacc;
    #pragma unroll
    for (int r = 0; r < 16; ++r) { o[0][r] = 0.f; o[1][r] = 0.f; lacc[r] = 0.f; }

    int mreg = 0;   // T14 state for mask

    auto issueKV = [&](int kt, int buf) {
        #pragma unroll
        for (int j = 0; j < 2; ++j) {
            const int rbase = w*16 + j*8;
            gld16(K + (size_t)(b*SS + kt*64 + rbase + grow)*HH + h*HDIM + cg*8,
                  &Ks[buf][rbase][0]);
            gld16(Vrows + (size_t)(rbase + grow)*SS + kt*64 + cg*8,
                  &Vs[buf][rbase][0]);
        }
    };
    auto issueM = [&](int kt) {
        if (t < 64) mreg = mask[(size_t)b*SS + kt*64 + t];
    };
    auto writeM = [&](int buf) {
        if (t < 64) madd[buf][t] = (mreg != 0) ? db2 : -1e30f;
    };

    // prologue: tile 0 fully staged before the first barrier
    issueKV(0, 0);
    issueM(0);
    writeM(0);

    for (int kt = 0; kt < SS/64; ++kt) {
        const int cur = kt & 1;
        __syncthreads();                 // buf[cur] ready (vmcnt+lgkm drained)
        const bool more = (kt + 1 < SS/64);
        if (more) { issueKV(kt + 1, cur ^ 1); issueM(kt + 1); }  // loads in flight

        #pragma unroll
        for (int kblk = 0; kblk < 2; ++kblk) {
            const u16* kb = &Ks[cur][kblk*32 + ql][0];

            // z init = madd[key] broadcast per row (C of the MFMA)
            floatx16 z;
            #pragma unroll
            for (int qq = 0; qq < 4; ++qq) {
                float4 mv = *(const float4*)&madd[cur][kblk*32 + qq*8 + 4*hi];
                z[qq*4+0] = mv.x; z[qq*4+1] = mv.y; z[qq*4+2] = mv.z; z[qq*4+3] = mv.w;
            }
            short8 kf[4];
            #pragma unroll
            for (int s = 0; s < 4; ++s)
                kf[s] = *(const short8*)(kb + ((s*2 + hi) ^ sw7)*8);
            __builtin_amdgcn_s_setprio(1);
            #pragma unroll
            for (int s = 0; s < 4; ++s)
                z = __builtin_amdgcn_mfma_f32_32x32x16_bf16(kf[s], qv[s], z, 0, 0, 0);
            __builtin_amdgcn_s_setprio(0);

            // p = exp2(z) in place
            #pragma unroll
            for (int r = 0; r < 16; ++r) z[r] = __builtin_amdgcn_exp2f(z[r]);

            // pack to PV A-frags + accumulate l and o
            #pragma unroll
            for (int ks = 0; ks < 2; ++ks) {
                unsigned x0 = pack_bf16x2(z[ks*8 + 0], z[ks*8 + 1]);
                unsigned y0 = pack_bf16x2(z[ks*8 + 4], z[ks*8 + 5]);
                unsigned x1 = pack_bf16x2(z[ks*8 + 2], z[ks*8 + 3]);
                unsigned y1 = pack_bf16x2(z[ks*8 + 6], z[ks*8 + 7]);
                uint2v s0 = __builtin_amdgcn_permlane32_swap(x0, y0, false, false);
                uint2v s1 = __builtin_amdgcn_permlane32_swap(x1, y1, false, false);
                uint4v pv; pv[0] = s0[0]; pv[1] = s1[0]; pv[2] = s0[1]; pv[3] = s1[1];
                short8 pa = __builtin_bit_cast(short8, pv);

                const int ck = kblk*4 + ks*2 + hi;     // 8-key chunk for this A-frag
                short8 vf0 = *(const short8*)&Vs[cur][ql][(ck ^ sw7)*8];
                short8 vf1 = *(const short8*)&Vs[cur][32 + ql][(ck ^ sw7)*8];

                __builtin_amdgcn_s_setprio(1);
                lacc = __builtin_amdgcn_mfma_f32_32x32x16_bf16(pa, ones, lacc, 0, 0, 0);
                o[0] = __builtin_amdgcn_mfma_f32_32x32x16_bf16(pa, vf0, o[0], 0, 0, 0);
                o[1] = __builtin_amdgcn_mfma_f32_32x32x16_bf16(pa, vf1, o[1], 0, 0, 0);
                __builtin_amdgcn_s_setprio(0);
            }
        }

        if (more) writeM(cur ^ 1);   // late madd write (mask load latency hidden)
    }

    // epilogue: lacc rows == o rows == query crow(r,hi); divide in-register
    #pragma unroll
    for (int r = 0; r < 16; ++r) {
        float l = lacc[r];
        float inv = (l > 0.f) ? 1.f / l : 0.f;
        const int qrow = q0 + w*32 + (r & 3) + 8*(r >> 2) + 4*hi;
        u16* dst = ctx + ((size_t)(b*SS + qrow))*HH + h*HDIM + ql;
        dst[0]  = f2bf(o[0][r] * inv);
        dst[32] = f2bf(o[1][r] * inv);
    }
}

// Wave-per-row LN: 4 rows/block, lane handles 12 contiguous elements.
__global__ __launch_bounds__(256) void add_ln_wave(
    const u16* __restrict__ proj, const float* __restrict__ resid,
    const float* __restrict__ gamma, const float* __restrict__ beta,
    float* __restrict__ out)
{
    const int t = threadIdx.x, w = t >> 6, lane = t & 63;
    const int row = blockIdx.x * 4 + w;
    const size_t base = (size_t)row * HH + lane * 12;
    const int gbase = lane * 12;

    float x[12];
    #pragma unroll
    for (int j = 0; j < 3; ++j) {
        ushort4 p = *(const ushort4*)(proj + base + j*4);
        float4  r = *(const float4*)(resid + base + j*4);
        x[j*4+0] = bf2f(p.x) + r.x;
        x[j*4+1] = bf2f(p.y) + r.y;
        x[j*4+2] = bf2f(p.z) + r.z;
        x[j*4+3] = bf2f(p.w) + r.w;
    }
    float s = 0.f, ss = 0.f;
    #pragma unroll
    for (int j = 0; j < 12; ++j) { s += x[j]; ss += x[j]*x[j]; }
    #pragma unroll
    for (int off = 1; off < 64; off <<= 1) {
        s  += __shfl_xor(s, off);
        ss += __shfl_xor(ss, off);
    }
    float mean = s * (1.f/768.f);
    float var  = ss * (1.f/768.f) - mean*mean;
    float rstd = rsqrtf(fmaxf(var, 0.f) + 1e-5f);
    #pragma unroll
    for (int j = 0; j < 3; ++j) {
        float4 g = *(const float4*)(gamma + gbase + j*4);
        float4 bt = *(const float4*)(beta + gbase + j*4);
        float4 y;
        y.x = (x[j*4+0]-mean)*rstd*g.x + bt.x;
        y.y = (x[j*4+1]-mean)*rstd*g.y + bt.y;
        y.z = (x[j*4+2]-mean)*rstd*g.z + bt.z;
        y.w = (x[j*4+3]-mean)*rstd*g.w + bt.w;
        *(float4*)(out + base + j*4) = y;
    }
}

extern "C" void kernel_launch(void* const* d_in, const int* in_sizes, int n_in,
                              void* d_out, int out_size, void* d_ws, size_t ws_size,
                              hipStream_t stream)
{
    (void)in_sizes; (void)n_in; (void)out_size;
    const float* x    = (const float*)d_in[0];
    const float* Wq   = (const float*)d_in[1];
    const float* bq   = (const float*)d_in[2];
    const float* Wk   = (const float*)d_in[3];
    const float* bk   = (const float*)d_in[4];
    const float* Wv   = (const float*)d_in[5];
    const float* bv   = (const float*)d_in[6];
    const float* Wo   = (const float*)d_in[7];
    const float* bo   = (const float*)d_in[8];
    const float* dimb = (const float*)d_in[9];
    const float* gam  = (const float*)d_in[10];
    const float* bet  = (const float*)d_in[11];
    const int* mask   = (const int*)d_in[12];
    const int* didx   = (const int*)d_in[13];

    const size_t N = (size_t)MM * HH;            // 6,291,456 elements
    if (ws_size < 4 * N * sizeof(u16)) return;   // 50.3 MB, proven
    u16* ws = (u16*)d_ws;
    u16* q    = ws;          // slot0: q, later proj
    u16* kbuf = ws + N;      // slot1
    u16* vbuf = ws + 2*N;    // slot2: v, later ctx
    u16* slot3 = ws + 3*N;   // xb during QKV GEMMs, then vt
    u16* xb   = slot3;
    u16* vtb  = slot3;
    u16* ctx  = vbuf;        // attn output overwrites original V
    u16* proj = q;

    const bool bigws = ws_size >= (4 * N + 4 * (size_t)WEL) * sizeof(u16);  // +4.7 MB
    u16* wb = ws + 4 * N;    // bf16 weights, contiguous (Wq;Wk;Wv;Wo) = 3072x768

    if (bigws) {
        cvt_all<<<XCVT_BLKS + 4*WCVT_BLKS, 256, 0, stream>>>(x, Wq, Wk, Wv, Wo, xb, wb);
        gemm_gld_qkv<<<dim3(3*HH/192, MM/128), 256, 0, stream>>>(
            xb, wb, bq, bk, bv, q, kbuf, vbuf);
    } else {
        f32_to_bf16<<<(int)(N/8/256), 256, 0, stream>>>(x, xb, (int)(N/8));
        dim3 gg(HH/64, MM/128);
        gemm_mfma_nt<<<gg, 256, 0, stream>>>(xb, Wq, bq, q);
        gemm_mfma_nt<<<gg, 256, 0, stream>>>(xb, Wk, bk, kbuf);
        gemm_mfma_nt<<<gg, 256, 0, stream>>>(xb, Wv, bv, vbuf);
    }
    // vbuf -> vt (slot3; xb is dead now). attn then writes ctx over vbuf.
    v_transpose<<<dim3(SS/64, NHEAD, BB), 256, 0, stream>>>(vbuf, vtb);
    attn_mfma32<<<dim3(SS/128, NHEAD, BB), 256, 0, stream>>>(q, kbuf, vtb, dimb, mask, didx, ctx);
    if (bigws) gemm_gld_m64<<<dim3(HH/128, MM/64), 256, 0, stream>>>(ctx, wb + 3*WEL, bo, proj);
    else {
        dim3 gg(HH/64, MM/128);
        gemm_mfma_nt<<<gg, 256, 0, stream>>>(ctx, Wo, bo, proj);
    }
    add_ln_wave<<<MM/4, 256, 0, stream>>>(proj, x, gam, bet, (float*)d_out);
}

// Round 8
// 237.036 us; speedup vs baseline: 1.0232x; 1.0232x over previous
//
#include <hip/hip_runtime.h>
#include <hip/hip_bf16.h>

// Inputs fp32, output fp32 (proven). Intermediates bf16 in ws.
#define HH    768
#define NHEAD 12
#define HDIM  64
#define BB    4
#define SS    2048
#define MM    (BB*SS)     // 8192 rows
#define NDIMS 5
#define WEL   (HH*HH)     // 589824 elements per weight matrix
#define LOG2E 1.44269504088896f
#define QSCALE 0.180336881f   // 0.125 * log2e

typedef unsigned short u16;
typedef __attribute__((ext_vector_type(8))) short short8;     // 8 bf16 (4 VGPRs)
typedef __attribute__((ext_vector_type(4))) float floatx4;    // 16x16 MFMA C/D
typedef __attribute__((ext_vector_type(16))) float floatx16;  // 32x32 MFMA C/D
typedef __attribute__((ext_vector_type(4))) unsigned int uint4v;
typedef __attribute__((ext_vector_type(2))) unsigned int uint2v;

__device__ __forceinline__ float bf2f(u16 u) {
    return __uint_as_float(((unsigned int)u) << 16);
}
__device__ __forceinline__ u16 f2bf(float f) {
    unsigned int x = __float_as_uint(f);
    unsigned int r = (x + 0x7fffu + ((x >> 16) & 1u)) >> 16;
    return (u16)r;
}
__device__ __forceinline__ unsigned int pack_bf16x2(float a, float b) {
    float2 f2 = make_float2(a, b);
    __hip_bfloat162 h2 = __float22bfloat162_rn(f2);
    return *reinterpret_cast<unsigned int*>(&h2);
}
// async global->LDS, 16 B per lane; LDS dest = wave-uniform base + lane*16
__device__ __forceinline__ void gld16(const u16* g, u16* l) {
    __builtin_amdgcn_global_load_lds(
        (const __attribute__((address_space(1))) unsigned int*)g,
        (__attribute__((address_space(3))) unsigned int*)l, 16, 0, 0);
}

// fp32 -> bf16, 8 elements/thread (fallback path)
__global__ __launch_bounds__(256) void f32_to_bf16(
    const float* __restrict__ in, u16* __restrict__ out, int n8)
{
    int i = blockIdx.x * 256 + threadIdx.x;
    if (i >= n8) return;
    float4 a = ((const float4*)in)[i*2];
    float4 b = ((const float4*)in)[i*2 + 1];
    ushort4 lo, hi;
    lo.x = f2bf(a.x); lo.y = f2bf(a.y); lo.z = f2bf(a.z); lo.w = f2bf(a.w);
    hi.x = f2bf(b.x); hi.y = f2bf(b.y); hi.z = f2bf(b.z); hi.w = f2bf(b.w);
    ((ushort4*)out)[i*2]     = lo;
    ((ushort4*)out)[i*2 + 1] = hi;
}

// Fused conversion: x (MM*HH) and 4 weight matrices -> bf16, one launch.
#define XCVT_BLKS ((MM*HH)/8/256)   // 3072
#define WCVT_BLKS (WEL/8/256)       // 288
__global__ __launch_bounds__(256) void cvt_all(
    const float* __restrict__ x,
    const float* __restrict__ W0, const float* __restrict__ W1,
    const float* __restrict__ W2, const float* __restrict__ W3,
    u16* __restrict__ xb, u16* __restrict__ wb)
{
    const int bid = blockIdx.x;
    const float* src;
    u16* dst;
    int i;
    if (bid < XCVT_BLKS) {
        src = x; dst = xb; i = bid * 256 + threadIdx.x;
    } else {
        const int wsel = (bid - XCVT_BLKS) / WCVT_BLKS;
        src = (wsel == 0) ? W0 : (wsel == 1) ? W1 : (wsel == 2) ? W2 : W3;
        dst = wb + (size_t)wsel * WEL;
        i = ((bid - XCVT_BLKS) % WCVT_BLKS) * 256 + threadIdx.x;
    }
    float4 a = ((const float4*)src)[i*2];
    float4 b = ((const float4*)src)[i*2 + 1];
    ushort4 lo, hi;
    lo.x = f2bf(a.x); lo.y = f2bf(a.y); lo.z = f2bf(a.z); lo.w = f2bf(a.w);
    hi.x = f2bf(b.x); hi.y = f2bf(b.y); hi.z = f2bf(b.z); hi.w = f2bf(b.w);
    ((ushort4*)dst)[i*2]     = lo;
    ((ushort4*)dst)[i*2 + 1] = hi;
}

// V [b*SS+key][h*64+d] bf16 -> vt [(b*12+h)*64+d][key] (fallback path only).
__global__ __launch_bounds__(256) void v_transpose(
    const u16* __restrict__ V, u16* __restrict__ vt)
{
    __shared__ unsigned Ls[64][36];
    const int t = threadIdx.x;
    const int kt = blockIdx.x, h = blockIdx.y, b = blockIdx.z;
    const int p  = t & 31;
    const int dg = (t >> 5) * 8;
    const u16* va = V + ((size_t)(b*SS + kt*64 + 2*p))*HH + h*HDIM + dg;
    const u16* vb = va + HH;
    uint4 A = *(const uint4*)va;
    uint4 Bv = *(const uint4*)vb;
    const unsigned* Aw = (const unsigned*)&A;
    const unsigned* Bw = (const unsigned*)&Bv;
    #pragma unroll
    for (int i = 0; i < 4; ++i) {
        unsigned a = Aw[i], c = Bw[i];
        Ls[dg + 2*i][p]     = (a & 0xffffu) | (c << 16);
        Ls[dg + 2*i + 1][p] = (a >> 16) | (c & 0xffff0000u);
    }
    __syncthreads();
    const int d = t >> 2, kc = (t & 3) * 8;
    uint4 o0 = *(const uint4*)&Ls[d][kc];
    uint4 o1 = *(const uint4*)&Ls[d][kc + 4];
    u16* dst = vt + ((size_t)((b*NHEAD + h)*HDIM + d))*SS + kt*64 + kc*2;
    *(uint4*)dst       = o0;
    *(uint4*)(dst + 8) = o1;
}

// ---- Fused QKV GEMM: 128x192 block, BK=64, global_load_lds staging,
// chunk-XOR-swizzled LDS. 4 waves (2Mx2N), each 64x96 via 32x32x16 MFMA.
// Grid 12x64 = 768 blocks = 3.0/CU; LDS 40 KB; launch_bounds(256,3).
// For V tiles (sel==2): MFMA operands SWAPPED -> D[row=d][col=key] = V^T in
// the accumulator for free; epilogue writes vt[(b*12+h)*64+d][key] directly
// (same 64B-segment coalescing as the normal C-write). mfma(A,B): D-rows
// index A's rows, D-cols index B's rows.
__global__ __launch_bounds__(256, 3) void gemm_gld_qkv(
    const u16* __restrict__ Xb, const u16* __restrict__ Wb3,
    const float* __restrict__ bq, const float* __restrict__ bk, const float* __restrict__ bv,
    u16* __restrict__ oq, u16* __restrict__ ok, u16* __restrict__ vt)
{
    __shared__ u16 Xs[128][64];   // 16 KB
    __shared__ u16 Ws[192][64];   // 24 KB
    const int t = threadIdx.x;
    const int w = t >> 6, lane = t & 63;
    const int wy = w >> 1, wx = w & 1;
    const int m = lane & 31, hh = lane >> 5;
    const int grow = lane >> 3;
    const int cg   = (lane & 7) ^ grow;

    // XCD-bijective swizzle: 768 = 8 XCDs x 96 = 8 i-panels x 12 j-tiles each.
    const int flat = blockIdx.x + 12 * blockIdx.y;
    const int swz  = (flat & 7) * 96 + (flat >> 3);
    const int j0 = (swz % 12) * 192;
    const int i0 = (swz / 12) * 128;
    const int sel = j0 / HH;                 // 0=q 1=k 2=v (tiles never straddle)
    const int lj  = j0 - sel * HH;
    const float* biasL = ((sel == 0) ? bq : (sel == 1) ? bk : bv) + lj;
    const u16* Wrows = Wb3 + (size_t)j0 * HH;

    floatx16 acc[2][3];
    #pragma unroll
    for (int am = 0; am < 2; ++am)
        #pragma unroll
        for (int bn = 0; bn < 3; ++bn)
            #pragma unroll
            for (int r = 0; r < 16; ++r) acc[am][bn][r] = 0.f;

    if (sel != 2) {
        for (int k0 = 0; k0 < HH; k0 += 64) {
            __syncthreads();
            #pragma unroll
            for (int j = 0; j < 4; ++j) {
                const int r = w*32 + j*8;
                gld16(Xb + (size_t)(i0 + r + grow)*HH + k0 + cg*8, &Xs[r][0]);
            }
            #pragma unroll
            for (int j = 0; j < 6; ++j) {
                const int r = w*48 + j*8;
                gld16(Wrows + (size_t)(r + grow)*HH + k0 + cg*8, &Ws[r][0]);
            }
            __syncthreads();

            #pragma unroll
            for (int kh = 0; kh < 4; ++kh) {
                const int ch = kh*2 + hh;
                short8 af[2], bf[3];
                #pragma unroll
                for (int am = 0; am < 2; ++am)
                    af[am] = *(const short8*)&Xs[wy*64 + am*32 + m][(ch ^ (m & 7))*8];
                #pragma unroll
                for (int bn = 0; bn < 3; ++bn)
                    bf[bn] = *(const short8*)&Ws[wx*96 + bn*32 + m][(ch ^ (m & 7))*8];
                #pragma unroll
                for (int am = 0; am < 2; ++am)
                    #pragma unroll
                    for (int bn = 0; bn < 3; ++bn)
                        acc[am][bn] = __builtin_amdgcn_mfma_f32_32x32x16_bf16(
                            af[am], bf[bn], acc[am][bn], 0, 0, 0);
            }
        }

        u16* outL = ((sel == 0) ? oq : ok) + lj;
        float bb[3];
        #pragma unroll
        for (int bn = 0; bn < 3; ++bn) bb[bn] = biasL[wx*96 + bn*32 + m];
        #pragma unroll
        for (int am = 0; am < 2; ++am)
            #pragma unroll
            for (int bn = 0; bn < 3; ++bn)
                #pragma unroll
                for (int r = 0; r < 16; ++r) {
                    int row = i0 + wy*64 + am*32 + (r & 3) + 8*(r >> 2) + 4*hh;
                    outL[(size_t)row*HH + wx*96 + bn*32 + m] = f2bf(acc[am][bn][r] + bb[bn]);
                }
    } else {
        // V tile: swapped operands -> acc = V^T fragment
        for (int k0 = 0; k0 < HH; k0 += 64) {
            __syncthreads();
            #pragma unroll
            for (int j = 0; j < 4; ++j) {
                const int r = w*32 + j*8;
                gld16(Xb + (size_t)(i0 + r + grow)*HH + k0 + cg*8, &Xs[r][0]);
            }
            #pragma unroll
            for (int j = 0; j < 6; ++j) {
                const int r = w*48 + j*8;
                gld16(Wrows + (size_t)(r + grow)*HH + k0 + cg*8, &Ws[r][0]);
            }
            __syncthreads();

            #pragma unroll
            for (int kh = 0; kh < 4; ++kh) {
                const int ch = kh*2 + hh;
                short8 af[2], bf[3];
                #pragma unroll
                for (int am = 0; am < 2; ++am)
                    af[am] = *(const short8*)&Xs[wy*64 + am*32 + m][(ch ^ (m & 7))*8];
                #pragma unroll
                for (int bn = 0; bn < 3; ++bn)
                    bf[bn] = *(const short8*)&Ws[wx*96 + bn*32 + m][(ch ^ (m & 7))*8];
                #pragma unroll
                for (int am = 0; am < 2; ++am)
                    #pragma unroll
                    for (int bn = 0; bn < 3; ++bn)
                        acc[am][bn] = __builtin_amdgcn_mfma_f32_32x32x16_bf16(
                            bf[bn], af[am], acc[am][bn], 0, 0, 0);
            }
        }

        // write V^T: row = b*768 + lj + wcol (wcol = wx*96+bn*32+crow(r,hh)),
        // col(key) = i0%SS + wy*64 + am*32 + m. 32 lanes -> 64 B segments.
        const int b_ = i0 / SS;
        const int key0 = (i0 % SS) + wy*64 + m;
        #pragma unroll
        for (int am = 0; am < 2; ++am)
            #pragma unroll
            for (int bn = 0; bn < 3; ++bn)
                #pragma unroll
                for (int qq = 0; qq < 4; ++qq) {
                    float4 bv4 = *(const float4*)&biasL[wx*96 + bn*32 + qq*8 + 4*hh];
                    const float* bvp = (const float*)&bv4;
                    #pragma unroll
                    for (int j = 0; j < 4; ++j) {
                        const int r = qq*4 + j;
                        const int wcol = wx*96 + bn*32 + qq*8 + 4*hh + j;
                        vt[(size_t)(b_*HH + lj + wcol)*SS + key0 + am*32] =
                            f2bf(acc[am][bn][r] + bvp[j]);
                    }
                }
    }
}

// Output-projection GEMM: M-tile=64, N-tile=128 -> grid (6,128)=768 blocks
// (3 blocks/CU). Same staging/swizzle pattern.
__global__ __launch_bounds__(256) void gemm_gld_m64(
    const u16* __restrict__ Xb, const u16* __restrict__ Wb,
    const float* __restrict__ bias, u16* __restrict__ out)
{
    __shared__ u16 Xs[64][64];    // 8 KB
    __shared__ u16 Ws[128][64];   // 16 KB
    const int t = threadIdx.x;
    const int w = t >> 6, lane = t & 63;
    const int m = lane & 31, hh = lane >> 5;
    const int grow = lane >> 3;
    const int cg   = (lane & 7) ^ grow;

    // XCD-bijective swizzle: 768 = 8 x 96; each XCD gets 16 full M-panels.
    const int flat = blockIdx.x + 6 * blockIdx.y;
    const int swz  = (flat & 7) * 96 + (flat >> 3);
    const int j0 = (swz % 6) * 128;
    const int i0 = (swz / 6) * 64;

    floatx16 acc[2];
    #pragma unroll
    for (int am = 0; am < 2; ++am)
        #pragma unroll
        for (int r = 0; r < 16; ++r) acc[am][r] = 0.f;

    for (int k0 = 0; k0 < HH; k0 += 64) {
        __syncthreads();
        #pragma unroll
        for (int j = 0; j < 2; ++j) {
            const int r = w*16 + j*8;
            gld16(Xb + (size_t)(i0 + r + grow)*HH + k0 + cg*8, &Xs[r][0]);
        }
        #pragma unroll
        for (int j = 0; j < 4; ++j) {
            const int r = w*32 + j*8;
            gld16(Wb + (size_t)(j0 + r + grow)*HH + k0 + cg*8, &Ws[r][0]);
        }
        __syncthreads();

        #pragma unroll
        for (int kh = 0; kh < 4; ++kh) {
            const int ch = kh*2 + hh;
            short8 af[2], bf;
            af[0] = *(const short8*)&Xs[m][(ch ^ (m & 7))*8];
            af[1] = *(const short8*)&Xs[32 + m][(ch ^ (m & 7))*8];
            bf    = *(const short8*)&Ws[w*32 + m][(ch ^ (m & 7))*8];
            acc[0] = __builtin_amdgcn_mfma_f32_32x32x16_bf16(af[0], bf, acc[0], 0, 0, 0);
            acc[1] = __builtin_amdgcn_mfma_f32_32x32x16_bf16(af[1], bf, acc[1], 0, 0, 0);
        }
    }

    const float bb = bias[j0 + w*32 + m];
    #pragma unroll
    for (int am = 0; am < 2; ++am)
        #pragma unroll
        for (int r = 0; r < 16; ++r) {
            int row = i0 + am*32 + (r & 3) + 8*(r >> 2) + 4*hh;
            out[(size_t)row*HH + j0 + w*32 + m] = f2bf(acc[am][r] + bb);
        }
}

// Fallback (small ws): W fp32, cvt during staging — round-6 proven 16x16x32 kernel.
__global__ __launch_bounds__(256) void gemm_mfma_nt(
    const u16* __restrict__ Xb, const float* __restrict__ W,
    const float* __restrict__ bias, u16* __restrict__ out)
{
    __shared__ u16 Xs[128][40];
    __shared__ u16 Wt[64][40];
    const int t = threadIdx.x;
    const int w = t >> 6, lane = t & 63;
    const int c = lane & 15, qd = lane >> 4;
    const int i0 = blockIdx.y * 128, j0 = blockIdx.x * 64;
    const int xrow = t >> 1, xoff = (t & 1) * 16;
    const int wn = t >> 2, woff = (t & 3) * 8;

    floatx4 acc[2][4];
    #pragma unroll
    for (int mt = 0; mt < 2; ++mt)
        #pragma unroll
        for (int nt = 0; nt < 4; ++nt) acc[mt][nt] = (floatx4){0.f,0.f,0.f,0.f};

    for (int k0 = 0; k0 < HH; k0 += 32) {
        uint4 xa  = *(const uint4*)(Xb + (size_t)(i0 + xrow)*HH + k0 + xoff);
        uint4 xb2 = *(const uint4*)(Xb + (size_t)(i0 + xrow)*HH + k0 + xoff + 8);
        float4 wa = *(const float4*)(W + (size_t)(j0 + wn)*HH + k0 + woff);
        float4 wb = *(const float4*)(W + (size_t)(j0 + wn)*HH + k0 + woff + 4);
        __syncthreads();
        *(uint4*)&Xs[xrow][xoff]     = xa;
        *(uint4*)&Xs[xrow][xoff + 8] = xb2;
        ushort4 w0, w1;
        w0.x = f2bf(wa.x); w0.y = f2bf(wa.y); w0.z = f2bf(wa.z); w0.w = f2bf(wa.w);
        w1.x = f2bf(wb.x); w1.y = f2bf(wb.y); w1.z = f2bf(wb.z); w1.w = f2bf(wb.w);
        *(ushort4*)&Wt[wn][woff]     = w0;
        *(ushort4*)&Wt[wn][woff + 4] = w1;
        __syncthreads();

        short8 a0 = *(const short8*)&Xs[w*32 + c][qd*8];
        short8 a1 = *(const short8*)&Xs[w*32 + 16 + c][qd*8];
        #pragma unroll
        for (int nt = 0; nt < 4; ++nt) {
            short8 bfr = *(const short8*)&Wt[nt*16 + c][qd*8];
            acc[0][nt] = __builtin_amdgcn_mfma_f32_16x16x32_bf16(a0, bfr, acc[0][nt], 0, 0, 0);
            acc[1][nt] = __builtin_amdgcn_mfma_f32_16x16x32_bf16(a1, bfr, acc[1][nt], 0, 0, 0);
        }
    }

    float bv[4];
    #pragma unroll
    for (int nt = 0; nt < 4; ++nt) bv[nt] = bias[j0 + nt*16 + c];
    #pragma unroll
    for (int mt = 0; mt < 2; ++mt)
        #pragma unroll
        for (int nt = 0; nt < 4; ++nt)
            #pragma unroll
            for (int r = 0; r < 4; ++r)
                out[(size_t)(i0 + w*32 + mt*16 + qd*4 + r)*HH + j0 + nt*16 + c] =
                    f2bf(acc[mt][nt][r] + bv[nt]);
}

// ---- 32x32 MFMA flash attention (QBLK=128, 768 blocks, 3 blocks/CU),
// in-register softmax (T12), XCD-bijective swizzle (T1), T5 setprio.
// V pre-transposed [(b*12+h)*64+d][key] -> staged via gld16 exactly like K.
__global__ __launch_bounds__(256, 3) void attn_mfma32(
    const u16* __restrict__ Q, const u16* __restrict__ K, const u16* __restrict__ vt,
    const float* __restrict__ dim_biases, const int* __restrict__ mask,
    const int* __restrict__ dim_idx_p, u16* __restrict__ ctx)
{
    __shared__ u16 Ks[2][64][64];    // [buf][key][d], chunk c holds global chunk c^(key&7)
    __shared__ u16 Vs[2][64][64];    // [buf][d][key], chunk c holds global chunk c^(d&7)
    __shared__ float madd[2][64];    // per-key: mask ? db2 : -1e30

    const int t = threadIdx.x;
    const int w = t >> 6, lane = t & 63;
    const int ql = lane & 31, hi = lane >> 5;
    const int sw7 = ql & 7;

    // XCD-bijective swizzle: 768 blocks = 8 XCDs x 96.
    const int flat = blockIdx.x + 16 * (blockIdx.y + 12 * blockIdx.z);
    const int swz  = (flat & 7) * 96 + (flat >> 3);
    const int q0 = (swz & 15) * 128;
    const int h  = (swz >> 4) % NHEAD;
    const int b  = swz / (16 * NHEAD);

    const int didx = *dim_idx_p;
    const float db2 = ((didx < NDIMS) ? dim_biases[didx*NHEAD + h] : 0.f) * LOG2E;

    // staging geometry (gld16): 8 rows x 8 chunks per instr, chunk-XOR swizzle
    const int grow = lane >> 3;
    const int cg   = (lane & 7) ^ grow;

    const u16* Vrows = vt + (size_t)(b*NHEAD + h)*HDIM*SS;   // 64 rows of SS keys

    short8 ones;
    #pragma unroll
    for (int j = 0; j < 8; ++j) ones[j] = (short)0x3F80;   // bf16 1.0

    // Q in registers: B-frag qv[s][j] = QSCALE * Q[q0+w*32+ql][s*16 + 8*hi + j]
    short8 qv[4];
    {
        const u16* qsrc = Q + ((size_t)(b*SS + q0 + w*32 + ql))*HH + h*HDIM + 8*hi;
        #pragma unroll
        for (int s = 0; s < 4; ++s) {
            ushort4 u0 = *(const ushort4*)(qsrc + s*16);
            ushort4 u1 = *(const ushort4*)(qsrc + s*16 + 4);
            const u16 uu[8] = {u0.x,u0.y,u0.z,u0.w,u1.x,u1.y,u1.z,u1.w};
            #pragma unroll
            for (int j = 0; j < 8; ++j)
                qv[s][j] = (short)f2bf(bf2f(uu[j]) * QSCALE);
        }
    }

    floatx16 o[2], lacc;
    #pragma unroll
    for (int r = 0; r < 16; ++r) { o[0][r] = 0.f; o[1][r] = 0.f; lacc[r] = 0.f; }

    int mreg = 0;   // T14 state for mask

    auto issueKV = [&](int kt, int buf) {
        #pragma unroll
        for (int j = 0; j < 2; ++j) {
            const int rbase = w*16 + j*8;
            gld16(K + (size_t)(b*SS + kt*64 + rbase + grow)*HH + h*HDIM + cg*8,
                  &Ks[buf][rbase][0]);
            gld16(Vrows + (size_t)(rbase + grow)*SS + kt*64 + cg*8,
                  &Vs[buf][rbase][0]);
        }
    };
    auto issueM = [&](int kt) {
        if (t < 64) mreg = mask[(size_t)b*SS + kt*64 + t];
    };
    auto writeM = [&](int buf) {
        if (t < 64) madd[buf][t] = (mreg != 0) ? db2 : -1e30f;
    };

    // prologue: tile 0 fully staged before the first barrier
    issueKV(0, 0);
    issueM(0);
    writeM(0);

    for (int kt = 0; kt < SS/64; ++kt) {
        const int cur = kt & 1;
        __syncthreads();                 // buf[cur] ready (vmcnt+lgkm drained)
        const bool more = (kt + 1 < SS/64);
        if (more) { issueKV(kt + 1, cur ^ 1); issueM(kt + 1); }  // loads in flight

        #pragma unroll
        for (int kblk = 0; kblk < 2; ++kblk) {
            const u16* kb = &Ks[cur][kblk*32 + ql][0];

            // z init = madd[key] broadcast per row (C of the MFMA)
            floatx16 z;
            #pragma unroll
            for (int qq = 0; qq < 4; ++qq) {
                float4 mv = *(const float4*)&madd[cur][kblk*32 + qq*8 + 4*hi];
                z[qq*4+0] = mv.x; z[qq*4+1] = mv.y; z[qq*4+2] = mv.z; z[qq*4+3] = mv.w;
            }
            short8 kf[4];
            #pragma unroll
            for (int s = 0; s < 4; ++s)
                kf[s] = *(const short8*)(kb + ((s*2 + hi) ^ sw7)*8);
            __builtin_amdgcn_s_setprio(1);
            #pragma unroll
            for (int s = 0; s < 4; ++s)
                z = __builtin_amdgcn_mfma_f32_32x32x16_bf16(kf[s], qv[s], z, 0, 0, 0);
            __builtin_amdgcn_s_setprio(0);

            // p = exp2(z) in place
            #pragma unroll
            for (int r = 0; r < 16; ++r) z[r] = __builtin_amdgcn_exp2f(z[r]);

            // pack to PV A-frags + accumulate l and o
            #pragma unroll
            for (int ks = 0; ks < 2; ++ks) {
                unsigned x0 = pack_bf16x2(z[ks*8 + 0], z[ks*8 + 1]);
                unsigned y0 = pack_bf16x2(z[ks*8 + 4], z[ks*8 + 5]);
                unsigned x1 = pack_bf16x2(z[ks*8 + 2], z[ks*8 + 3]);
                unsigned y1 = pack_bf16x2(z[ks*8 + 6], z[ks*8 + 7]);
                uint2v s0 = __builtin_amdgcn_permlane32_swap(x0, y0, false, false);
                uint2v s1 = __builtin_amdgcn_permlane32_swap(x1, y1, false, false);
                uint4v pv; pv[0] = s0[0]; pv[1] = s1[0]; pv[2] = s0[1]; pv[3] = s1[1];
                short8 pa = __builtin_bit_cast(short8, pv);

                const int ck = kblk*4 + ks*2 + hi;     // 8-key chunk for this A-frag
                short8 vf0 = *(const short8*)&Vs[cur][ql][(ck ^ sw7)*8];
                short8 vf1 = *(const short8*)&Vs[cur][32 + ql][(ck ^ sw7)*8];

                __builtin_amdgcn_s_setprio(1);
                lacc = __builtin_amdgcn_mfma_f32_32x32x16_bf16(pa, ones, lacc, 0, 0, 0);
                o[0] = __builtin_amdgcn_mfma_f32_32x32x16_bf16(pa, vf0, o[0], 0, 0, 0);
                o[1] = __builtin_amdgcn_mfma_f32_32x32x16_bf16(pa, vf1, o[1], 0, 0, 0);
                __builtin_amdgcn_s_setprio(0);
            }
        }

        if (more) writeM(cur ^ 1);   // late madd write (mask load latency hidden)
    }

    // epilogue: lacc rows == o rows == query crow(r,hi); divide in-register
    #pragma unroll
    for (int r = 0; r < 16; ++r) {
        float l = lacc[r];
        float inv = (l > 0.f) ? 1.f / l : 0.f;
        const int qrow = q0 + w*32 + (r & 3) + 8*(r >> 2) + 4*hi;
        u16* dst = ctx + ((size_t)(b*SS + qrow))*HH + h*HDIM + ql;
        dst[0]  = f2bf(o[0][r] * inv);
        dst[32] = f2bf(o[1][r] * inv);
    }
}

// Wave-per-row LN: 4 rows/block, lane handles 12 contiguous elements.
__global__ __launch_bounds__(256) void add_ln_wave(
    const u16* __restrict__ proj, const float* __restrict__ resid,
    const float* __restrict__ gamma, const float* __restrict__ beta,
    float* __restrict__ out)
{
    const int t = threadIdx.x, w = t >> 6, lane = t & 63;
    const int row = blockIdx.x * 4 + w;
    const size_t base = (size_t)row * HH + lane * 12;
    const int gbase = lane * 12;

    float x[12];
    #pragma unroll
    for (int j = 0; j < 3; ++j) {
        ushort4 p = *(const ushort4*)(proj + base + j*4);
        float4  r = *(const float4*)(resid + base + j*4);
        x[j*4+0] = bf2f(p.x) + r.x;
        x[j*4+1] = bf2f(p.y) + r.y;
        x[j*4+2] = bf2f(p.z) + r.z;
        x[j*4+3] = bf2f(p.w) + r.w;
    }
    float s = 0.f, ss = 0.f;
    #pragma unroll
    for (int j = 0; j < 12; ++j) { s += x[j]; ss += x[j]*x[j]; }
    #pragma unroll
    for (int off = 1; off < 64; off <<= 1) {
        s  += __shfl_xor(s, off);
        ss += __shfl_xor(ss, off);
    }
    float mean = s * (1.f/768.f);
    float var  = ss * (1.f/768.f) - mean*mean;
    float rstd = rsqrtf(fmaxf(var, 0.f) + 1e-5f);
    #pragma unroll
    for (int j = 0; j < 3; ++j) {
        float4 g = *(const float4*)(gamma + gbase + j*4);
        float4 bt = *(const float4*)(beta + gbase + j*4);
        float4 y;
        y.x = (x[j*4+0]-mean)*rstd*g.x + bt.x;
        y.y = (x[j*4+1]-mean)*rstd*g.y + bt.y;
        y.z = (x[j*4+2]-mean)*rstd*g.z + bt.z;
        y.w = (x[j*4+3]-mean)*rstd*g.w + bt.w;
        *(float4*)(out + base + j*4) = y;
    }
}

extern "C" void kernel_launch(void* const* d_in, const int* in_sizes, int n_in,
                              void* d_out, int out_size, void* d_ws, size_t ws_size,
                              hipStream_t stream)
{
    (void)in_sizes; (void)n_in; (void)out_size;
    const float* x    = (const float*)d_in[0];
    const float* Wq   = (const float*)d_in[1];
    const float* bq   = (const float*)d_in[2];
    const float* Wk   = (const float*)d_in[3];
    const float* bk   = (const float*)d_in[4];
    const float* Wv   = (const float*)d_in[5];
    const float* bv   = (const float*)d_in[6];
    const float* Wo   = (const float*)d_in[7];
    const float* bo   = (const float*)d_in[8];
    const float* dimb = (const float*)d_in[9];
    const float* gam  = (const float*)d_in[10];
    const float* bet  = (const float*)d_in[11];
    const int* mask   = (const int*)d_in[12];
    const int* didx   = (const int*)d_in[13];

    const size_t N = (size_t)MM * HH;            // 6,291,456 elements
    if (ws_size < 4 * N * sizeof(u16)) return;   // 50.3 MB, proven
    u16* ws = (u16*)d_ws;
    u16* q    = ws;          // slot0: q, later proj
    u16* kbuf = ws + N;      // slot1
    u16* vtb  = ws + 2*N;    // slot2: V^T (written directly by QKV GEMM)
    u16* slot3 = ws + 3*N;   // xb during QKV GEMMs, then ctx
    u16* xb   = slot3;
    u16* ctx  = slot3;       // xb dead after QKV GEMM
    u16* proj = q;           // q dead after attn

    const bool bigws = ws_size >= (4 * N + 4 * (size_t)WEL) * sizeof(u16);  // +4.7 MB
    u16* wb = ws + 4 * N;    // bf16 weights, contiguous (Wq;Wk;Wv;Wo) = 3072x768

    if (bigws) {
        cvt_all<<<XCVT_BLKS + 4*WCVT_BLKS, 256, 0, stream>>>(x, Wq, Wk, Wv, Wo, xb, wb);
        gemm_gld_qkv<<<dim3(3*HH/192, MM/128), 256, 0, stream>>>(
            xb, wb, bq, bk, bv, q, kbuf, vtb);
        attn_mfma32<<<dim3(SS/128, NHEAD, BB), 256, 0, stream>>>(q, kbuf, vtb, dimb, mask, didx, ctx);
        gemm_gld_m64<<<dim3(HH/128, MM/64), 256, 0, stream>>>(ctx, wb + 3*WEL, bo, proj);
    } else {
        f32_to_bf16<<<(int)(N/8/256), 256, 0, stream>>>(x, xb, (int)(N/8));
        dim3 gg(HH/64, MM/128);
        gemm_mfma_nt<<<gg, 256, 0, stream>>>(xb, Wq, bq, q);
        gemm_mfma_nt<<<gg, 256, 0, stream>>>(xb, Wk, bk, kbuf);
        // V row-major into a temp region (reuse wb area is absent; use vtb then
        // transpose into slot3 after xb is dead? xb needed for all 3 gemms).
        // Fallback: V row-major -> vtb; transpose vtb -> slot3 (xb dead after).
        gemm_mfma_nt<<<gg, 256, 0, stream>>>(xb, Wv, bv, vtb);
        v_transpose<<<dim3(SS/64, NHEAD, BB), 256, 0, stream>>>(vtb, slot3);
        // now slot3 holds V^T; attn writes ctx over vtb (slot2)
        attn_mfma32<<<dim3(SS/128, NHEAD, BB), 256, 0, stream>>>(q, kbuf, slot3, dimb, mask, didx, vtb);
        gemm_mfma_nt<<<dim3(HH/64, MM/128), 256, 0, stream>>>(vtb, Wo, bo, proj);
    }
    add_ln_wave<<<MM/4, 256, 0, stream>>>(proj, x, gam, bet, (float*)d_out);
}